// Round 1
// baseline (594.003 us; speedup 1.0000x reference)
//
#include <hip/hip_runtime.h>
#include <math.h>

#define NN 8192
#define DD 256
#define MARGIN 0.2f

// ---- mining kernel geometry ----
#define BM 128               // anchors per block
#define BN 128               // candidates per tile
#define BK 32                // k-chunk
#define SLICES 16            // candidate slices (grid.x)
#define CPB (NN / SLICES)    // 512 candidates per block
#define TILES (CPB / BN)     // 4 tiles per block

// chunk swizzle: permutes 16B chunks within a 128-float LDS row so that
// B-fragment ds_read_b128 across tx=0..15 is 2-way (free) instead of 4-way.
__device__ __forceinline__ int swzc(int ch) { return ch ^ (ch >> 3); }

// ---------------- kernel 1: inverse norms ----------------
__global__ void knorm(const float* __restrict__ emb, float* __restrict__ invn) {
    const int wave = threadIdx.x >> 6;
    const int lane = threadIdx.x & 63;
    const int row  = blockIdx.x * 4 + wave;
    const float4 v = *(const float4*)&emb[row * DD + lane * 4];
    float ss = v.x * v.x + v.y * v.y + v.z * v.z + v.w * v.w;
#pragma unroll
    for (int off = 1; off < 64; off <<= 1) ss += __shfl_xor(ss, off);
    if (lane == 0) invn[row] = 1.0f / fmaxf(sqrtf(ss), 1e-12f);
}

// ---------------- kernel 2: first same-label index ----------------
__global__ void kpos(const int* __restrict__ labels, int* __restrict__ posidx) {
    const int i = blockIdx.x * blockDim.x + threadIdx.x;
    const int li = labels[i];
    int p = -1;
    for (int j = 0; j < NN; ++j) {
        if (j != i && labels[j] == li) { p = j; break; }
    }
    posidx[i] = p;
}

// ---------------- kernel 3: d_ap per anchor ----------------
__global__ void kdap(const float* __restrict__ emb, const float* __restrict__ invn,
                     const int* __restrict__ posidx, float* __restrict__ dap) {
    const int i = blockIdx.x;
    const int lane = threadIdx.x;  // 64 threads
    const int p = posidx[i];
    float dv = 0.0f;
    if (p >= 0) {   // uniform across block
        const float4 a = *(const float4*)&emb[i * DD + lane * 4];
        const float4 b = *(const float4*)&emb[p * DD + lane * 4];
        float s = a.x * b.x + a.y * b.y + a.z * b.z + a.w * b.w;
#pragma unroll
        for (int off = 1; off < 64; off <<= 1) s += __shfl_xor(s, off);
        const float sim = s * invn[i] * invn[p];
        dv = fminf(fmaxf(1.0f - sim, 0.0f), 2.0f);
    }
    if (lane == 0) dap[i] = dv;
}

// ---------------- kernel 4: semi-hard mining (the N^2*D work) ----------------
__global__ __launch_bounds__(256) void kmain(
    const float* __restrict__ emb, const float* __restrict__ invn,
    const int* __restrict__ labels, const float* __restrict__ dap,
    float* __restrict__ minSemi, float* __restrict__ minNeg)
{
    __shared__ float As[BK][BM];   // k-major, transposed, chunk-swizzled cols
    __shared__ float Bs[BK][BN];
    __shared__ int   Ls[BN];
    __shared__ int   La[BM];
    __shared__ float Da[BM];

    const int tid = threadIdx.x;
    const int tx = tid & 15;       // candidate group 0..15
    const int ty = tid >> 4;       // anchor group 0..15
    const int slice = blockIdx.x;
    const int a0 = blockIdx.y * BM;

    if (tid < BM) {
        La[tid] = labels[a0 + tid];
        Da[tid] = dap[a0 + tid];
    }

    float mS[8], mN[8];
#pragma unroll
    for (int i = 0; i < 8; ++i) { mS[i] = INFINITY; mN[i] = INFINITY; }

    // swizzled fragment column bases (k-independent)
    const int ca0 = swzc(ty * 2) << 2;
    const int ca1 = swzc(ty * 2 + 1) << 2;
    const int cb0 = swzc(tx * 2) << 2;
    const int cb1 = swzc(tx * 2 + 1) << 2;

    float acc[8][8];
#pragma unroll
    for (int i = 0; i < 8; ++i)
#pragma unroll
        for (int j = 0; j < 8; ++j) acc[i][j] = 0.0f;

    for (int tile = 0; tile < TILES; ++tile) {
        const int c0 = slice * CPB + tile * BN;

        for (int kc = 0; kc < DD / BK; ++kc) {
            __syncthreads();   // prev compute / prev epilogue done
            if (kc == 0 && tid < BN) Ls[tid] = labels[c0 + tid];
            // stage transposed+normalized A,B chunks: 128 rows x 32 k each
            {
                const int kl = (tid & 7) * 4;   // k offset within chunk
                const int rl = tid >> 3;        // 0..31
#pragma unroll
                for (int p = 0; p < 4; ++p) {
                    const int row = p * 32 + rl;
                    const int sc = (swzc(row >> 2) << 2) | (row & 3);
                    {
                        const int gr = a0 + row;
                        const float4 v = *(const float4*)&emb[gr * DD + kc * BK + kl];
                        const float s = invn[gr];
                        As[kl + 0][sc] = v.x * s;
                        As[kl + 1][sc] = v.y * s;
                        As[kl + 2][sc] = v.z * s;
                        As[kl + 3][sc] = v.w * s;
                    }
                    {
                        const int gr = c0 + row;
                        const float4 v = *(const float4*)&emb[gr * DD + kc * BK + kl];
                        const float s = invn[gr];
                        Bs[kl + 0][sc] = v.x * s;
                        Bs[kl + 1][sc] = v.y * s;
                        Bs[kl + 2][sc] = v.z * s;
                        Bs[kl + 3][sc] = v.w * s;
                    }
                }
            }
            __syncthreads();
#pragma unroll 4
            for (int k = 0; k < BK; ++k) {
                const float4 A0 = *(const float4*)&As[k][ca0];
                const float4 A1 = *(const float4*)&As[k][ca1];
                const float4 B0 = *(const float4*)&Bs[k][cb0];
                const float4 B1 = *(const float4*)&Bs[k][cb1];
                const float av[8] = {A0.x, A0.y, A0.z, A0.w, A1.x, A1.y, A1.z, A1.w};
                const float bv[8] = {B0.x, B0.y, B0.z, B0.w, B1.x, B1.y, B1.z, B1.w};
#pragma unroll
                for (int i = 0; i < 8; ++i)
#pragma unroll
                    for (int j = 0; j < 8; ++j)
                        acc[i][j] = fmaf(av[i], bv[j], acc[i][j]);
            }
        }

        // tile epilogue: dist + mask + running mins; reset acc
        int la[8]; float da[8]; int lc[8];
#pragma unroll
        for (int i = 0; i < 8; ++i) { la[i] = La[ty * 8 + i]; da[i] = Da[ty * 8 + i]; }
#pragma unroll
        for (int j = 0; j < 8; ++j) lc[j] = Ls[tx * 8 + j];
#pragma unroll
        for (int i = 0; i < 8; ++i) {
#pragma unroll
            for (int j = 0; j < 8; ++j) {
                const float dd = fminf(fmaxf(1.0f - acc[i][j], 0.0f), 2.0f);
                acc[i][j] = 0.0f;
                if (lc[j] != la[i]) {
                    mN[i] = fminf(mN[i], dd);
                    if (dd > da[i] && dd < da[i] + MARGIN) mS[i] = fminf(mS[i], dd);
                }
            }
        }
    }

    // reduce across the 16 tx-lanes sharing each anchor group (contiguous lanes)
#pragma unroll
    for (int i = 0; i < 8; ++i) {
#pragma unroll
        for (int off = 1; off < 16; off <<= 1) {
            mN[i] = fminf(mN[i], __shfl_xor(mN[i], off));
            mS[i] = fminf(mS[i], __shfl_xor(mS[i], off));
        }
        if (tx == 0) {
            const int arow = a0 + ty * 8 + i;
            minNeg[arow * SLICES + slice]  = mN[i];
            minSemi[arow * SLICES + slice] = mS[i];
        }
    }
}

// ---------------- kernel 5: combine slices -> per-block partial sums ----------------
__global__ void kcombine(const int* __restrict__ posidx, const float* __restrict__ dap,
                         const float* __restrict__ minSemi, const float* __restrict__ minNeg,
                         float* __restrict__ partials)
{
    const int i = blockIdx.x * blockDim.x + threadIdx.x;
    float loss = 0.0f, cnt = 0.0f;
    if (posidx[i] >= 0) {
        float ms = INFINITY, mn = INFINITY;
#pragma unroll
        for (int s = 0; s < SLICES; ++s) {
            ms = fminf(ms, minSemi[i * SLICES + s]);
            mn = fminf(mn, minNeg[i * SLICES + s]);
        }
        const float dan = (ms < INFINITY) ? ms : mn;  // has_semi ? min semi : hardest
        loss = fmaxf(dap[i] - dan + MARGIN, 0.0f);
        cnt = 1.0f;
    }
#pragma unroll
    for (int off = 1; off < 64; off <<= 1) {
        loss += __shfl_xor(loss, off);
        cnt  += __shfl_xor(cnt, off);
    }
    __shared__ float sl[4], sc[4];
    const int wave = threadIdx.x >> 6, lane = threadIdx.x & 63;
    if (lane == 0) { sl[wave] = loss; sc[wave] = cnt; }
    __syncthreads();
    if (threadIdx.x == 0) {
        partials[blockIdx.x]      = sl[0] + sl[1] + sl[2] + sl[3];
        partials[32 + blockIdx.x] = sc[0] + sc[1] + sc[2] + sc[3];
    }
}

// ---------------- kernel 6: final scalar ----------------
__global__ void kfinal(const float* __restrict__ partials, float* __restrict__ out) {
    const int t = threadIdx.x;  // 64
    float L = (t < 32) ? partials[t] : 0.0f;
    float C = (t < 32) ? partials[32 + t] : 0.0f;
#pragma unroll
    for (int off = 1; off < 64; off <<= 1) {
        L += __shfl_xor(L, off);
        C += __shfl_xor(C, off);
    }
    if (t == 0) out[0] = (C > 0.0f) ? (L / C) : 0.0f;
}

extern "C" void kernel_launch(void* const* d_in, const int* in_sizes, int n_in,
                              void* d_out, int out_size, void* d_ws, size_t ws_size,
                              hipStream_t stream) {
    const float* emb   = (const float*)d_in[0];
    const int* labels  = (const int*)d_in[1];
    float* out = (float*)d_out;

    float* ws   = (float*)d_ws;
    float* invn = ws;                         // NN floats
    float* dapv = ws + NN;                    // NN floats
    int*   posi = (int*)(ws + 2 * NN);        // NN ints
    float* minS = ws + 3 * NN;                // NN*SLICES floats
    float* minN = minS + NN * SLICES;         // NN*SLICES floats
    float* parts = minN + NN * SLICES;        // 64 floats

    knorm<<<NN / 4, 256, 0, stream>>>(emb, invn);
    kpos<<<NN / 256, 256, 0, stream>>>(labels, posi);
    kdap<<<NN, 64, 0, stream>>>(emb, invn, posi, dapv);
    kmain<<<dim3(SLICES, NN / BM), 256, 0, stream>>>(emb, invn, labels, dapv, minS, minN);
    kcombine<<<NN / 256, 256, 0, stream>>>(posi, dapv, minS, minN, parts);
    kfinal<<<1, 64, 0, stream>>>(parts, out);
}

// Round 2
// 172.219 us; speedup vs baseline: 3.4491x; 3.4491x over previous
//
#include <hip/hip_runtime.h>
#include <math.h>

#define NN 8192
#define DD 256
#define MARGIN 0.2f
#define SL 16            // candidate slices (grid.x)
#define CPS (NN / SL)    // 512 candidates per slice
#define TILES (CPS / 128)

typedef __attribute__((ext_vector_type(8))) short bf16x8;  // 8 bf16 (4 VGPRs)
typedef __attribute__((ext_vector_type(4))) float f32x4;
typedef unsigned int u32;
typedef unsigned short u16;

static __device__ __forceinline__ u16 f2bf(float f) {   // RNE fp32 -> bf16
    u32 u = __float_as_uint(f);
    return (u16)((u + 0x7fffu + ((u >> 16) & 1u)) >> 16);
}

static __device__ __forceinline__ void gload16(const void* g, void* l) {
    __builtin_amdgcn_global_load_lds((const __attribute__((address_space(1))) void*)g,
                                     (__attribute__((address_space(3))) void*)l, 16, 0, 0);
}

// ---------- kernel 1: norms + normalized bf16 matrix ----------
__global__ void kprep(const float* __restrict__ emb, u16* __restrict__ ENb,
                      float* __restrict__ invn) {
    const int wid = threadIdx.x >> 6, l = threadIdx.x & 63;
    const int row = blockIdx.x * 4 + wid;
    const float4 v = *(const float4*)&emb[(size_t)row * DD + l * 4];
    float ss = v.x * v.x + v.y * v.y + v.z * v.z + v.w * v.w;
#pragma unroll
    for (int o = 1; o < 64; o <<= 1) ss += __shfl_xor(ss, o);
    const float inv = 1.0f / fmaxf(sqrtf(ss), 1e-12f);
    if (l == 0) invn[row] = inv;
    ushort4 o4;
    o4.x = f2bf(v.x * inv); o4.y = f2bf(v.y * inv);
    o4.z = f2bf(v.z * inv); o4.w = f2bf(v.w * inv);
    *(ushort4*)&ENb[(size_t)row * DD + l * 4] = o4;
}

// ---------- kernel 2: first same-label index (LDS-staged labels) ----------
__global__ void kpos(const int* __restrict__ labels, int* __restrict__ posidx) {
    __shared__ int L[NN];
    for (int j = threadIdx.x; j < NN; j += 256) L[j] = labels[j];
    __syncthreads();
    const int i = blockIdx.x * 256 + threadIdx.x;
    const int li = L[i];
    int p = -1;
    for (int j = 0; j < NN; ++j) {
        if (j != i && L[j] == li) { p = j; break; }
    }
    posidx[i] = p;
}

// ---------- kernel 3: exact fp32 d_ap ----------
__global__ void kdap(const float* __restrict__ emb, const float* __restrict__ invn,
                     const int* __restrict__ posidx, float* __restrict__ dap) {
    const int wid = threadIdx.x >> 6, l = threadIdx.x & 63;
    const int i = blockIdx.x * 4 + wid;
    const int p = posidx[i];
    float dv = 0.0f;
    if (p >= 0) {   // uniform per wave
        const float4 a = *(const float4*)&emb[(size_t)i * DD + l * 4];
        const float4 b = *(const float4*)&emb[(size_t)p * DD + l * 4];
        float s = a.x * b.x + a.y * b.y + a.z * b.z + a.w * b.w;
#pragma unroll
        for (int o = 1; o < 64; o <<= 1) s += __shfl_xor(s, o);
        const float sim = s * invn[i] * invn[p];
        dv = fminf(fmaxf(1.0f - sim, 0.0f), 2.0f);
    }
    if (l == 0) dap[i] = dv;
}

// ---------- kernel 4: MFMA mining ----------
// Per anchor, streaming sim-space maxes: MN = max sim over negatives,
// M1 = max sim over negatives with sim < hi (hi = 1 - d_ap).
__global__ __launch_bounds__(256) void kmine(
    const u16* __restrict__ ENb, const int* __restrict__ labels,
    const float* __restrict__ dap, float* __restrict__ pM1, float* __restrict__ pMN)
{
    __shared__ __align__(16) u16 As[128 * 64];   // candidates tile, chunk-swizzled
    __shared__ __align__(16) u16 Bs[128 * 64];   // anchors tile, chunk-swizzled
    __shared__ float Hi[128];
    __shared__ int LabA[128], LabC[128];
    __shared__ float RedN[2][128], RedS[2][128];

    const int tid = threadIdx.x;
    const int l = tid & 63;
    const int wid = tid >> 6;
    const int wr = wid >> 1;      // candidate half (M)
    const int wc = wid & 1;       // anchor half (N)
    const int slice = blockIdx.x;
    const int a0 = blockIdx.y * 128;

    if (tid < 128) {
        Hi[tid] = 1.0f - dap[a0 + tid];
        LabA[tid] = labels[a0 + tid];
    }

    const int frow = l & 15;      // row within 16x16 subtile
    const int fq = l >> 4;        // k-quarter 0..3
    const int fj = l & 7;         // row&7 for swizzle

    float mN[4], m1[4];
    int la[4]; float hiv[4];
#pragma unroll
    for (int n = 0; n < 4; ++n) { mN[n] = -INFINITY; m1[n] = -INFINITY; }

    f32x4 acc[4][4];

    for (int t = 0; t < TILES; ++t) {
        const int c0 = slice * CPS + t * 128;
#pragma unroll
        for (int m = 0; m < 4; ++m)
#pragma unroll
            for (int n = 0; n < 4; ++n) acc[m][n] = (f32x4){0.f, 0.f, 0.f, 0.f};

        for (int kc = 0; kc < 4; ++kc) {
            __syncthreads();     // prev compute/epilogue done; LDS reusable
            if (kc == 0 && tid < 128) LabC[tid] = labels[c0 + tid];
            // stage A,B: 1024 16B-chunks each; linear LDS dest, swizzled SOURCE
#pragma unroll
            for (int it = 0; it < 4; ++it) {
                const int idx = it * 256 + tid;
                const int row = idx >> 3;
                const int pch = idx & 7;
                const int lch = pch ^ (row & 7);
                gload16(&ENb[(size_t)(c0 + row) * DD + kc * 64 + lch * 8], &As[idx * 8]);
                gload16(&ENb[(size_t)(a0 + row) * DD + kc * 64 + lch * 8], &Bs[idx * 8]);
            }
            __syncthreads();     // staging drained (compiler emits vmcnt(0))
#pragma unroll
            for (int h = 0; h < 2; ++h) {
                bf16x8 af[4], bf[4];
                const int p = (4 * h + fq) ^ fj;   // physical chunk (swizzle-matched)
#pragma unroll
                for (int m = 0; m < 4; ++m)
                    af[m] = *(const bf16x8*)&As[(wr * 64 + m * 16 + frow) * 64 + p * 8];
#pragma unroll
                for (int n = 0; n < 4; ++n)
                    bf[n] = *(const bf16x8*)&Bs[(wc * 64 + n * 16 + frow) * 64 + p * 8];
#pragma unroll
                for (int m = 0; m < 4; ++m)
#pragma unroll
                    for (int n = 0; n < 4; ++n)
                        acc[m][n] = __builtin_amdgcn_mfma_f32_16x16x32_bf16(
                            af[m], bf[n], acc[m][n], 0, 0, 0);
            }
        }
        if (t == 0) {   // per-anchor constants (written pre-barrier at kernel start)
#pragma unroll
            for (int n = 0; n < 4; ++n) {
                la[n] = LabA[wc * 64 + n * 16 + frow];
                hiv[n] = Hi[wc * 64 + n * 16 + frow];
            }
        }
        int lcv[16];   // candidate labels for this tile: row = wr*64+m*16+fq*4+r
#pragma unroll
        for (int m = 0; m < 4; ++m)
#pragma unroll
            for (int r = 0; r < 4; ++r)
                lcv[m * 4 + r] = LabC[wr * 64 + m * 16 + fq * 4 + r];
        // epilogue: 6 VALU per element
#pragma unroll
        for (int m = 0; m < 4; ++m)
#pragma unroll
            for (int n = 0; n < 4; ++n) {
#pragma unroll
                for (int r = 0; r < 4; ++r) {
                    const float s = acc[m][n][r];
                    const float sel = (lcv[m * 4 + r] != la[n]) ? s : -INFINITY;
                    mN[n] = fmaxf(mN[n], sel);
                    const float sel2 = (sel < hiv[n]) ? sel : -INFINITY;
                    m1[n] = fmaxf(m1[n], sel2);
                }
            }
    }

    // reduce the 4 candidate row-groups (lanes l, l^16, l^32, l^48 share anchor)
#pragma unroll
    for (int n = 0; n < 4; ++n) {
        mN[n] = fmaxf(mN[n], __shfl_xor(mN[n], 16));
        mN[n] = fmaxf(mN[n], __shfl_xor(mN[n], 32));
        m1[n] = fmaxf(m1[n], __shfl_xor(m1[n], 16));
        m1[n] = fmaxf(m1[n], __shfl_xor(m1[n], 32));
    }
    __syncthreads();
    if (fq == 0) {
#pragma unroll
        for (int n = 0; n < 4; ++n) {
            RedN[wr][wc * 64 + n * 16 + frow] = mN[n];
            RedS[wr][wc * 64 + n * 16 + frow] = m1[n];
        }
    }
    __syncthreads();
    if (tid < 128) {   // combine the two candidate halves, write partials
        pMN[slice * NN + a0 + tid] = fmaxf(RedN[0][tid], RedN[1][tid]);
        pM1[slice * NN + a0 + tid] = fmaxf(RedS[0][tid], RedS[1][tid]);
    }
}

// ---------- kernel 5: combine slices -> per-block partial sums ----------
__global__ void kcombine(const int* __restrict__ posidx, const float* __restrict__ dap,
                         const float* __restrict__ pM1, const float* __restrict__ pMN,
                         float* __restrict__ partials)
{
    const int i = blockIdx.x * 256 + threadIdx.x;
    float loss = 0.0f, cnt = 0.0f;
    if (posidx[i] >= 0) {
        float s1 = -INFINITY, sN = -INFINITY;
#pragma unroll
        for (int s = 0; s < SL; ++s) {
            s1 = fmaxf(s1, pM1[s * NN + i]);
            sN = fmaxf(sN, pMN[s * NN + i]);
        }
        const float da = dap[i];
        const float lo = 1.0f - da - MARGIN;
        const float M = (s1 > lo) ? s1 : sN;   // has_semi ? best semi : hardest
        const float dan = fminf(fmaxf(1.0f - M, 0.0f), 2.0f);
        loss = fmaxf(da - dan + MARGIN, 0.0f);
        cnt = 1.0f;
    }
#pragma unroll
    for (int off = 1; off < 64; off <<= 1) {
        loss += __shfl_xor(loss, off);
        cnt  += __shfl_xor(cnt, off);
    }
    __shared__ float sl[4], sc[4];
    const int wave = threadIdx.x >> 6, lane = threadIdx.x & 63;
    if (lane == 0) { sl[wave] = loss; sc[wave] = cnt; }
    __syncthreads();
    if (threadIdx.x == 0) {
        partials[blockIdx.x]      = sl[0] + sl[1] + sl[2] + sl[3];
        partials[32 + blockIdx.x] = sc[0] + sc[1] + sc[2] + sc[3];
    }
}

// ---------- kernel 6: final scalar ----------
__global__ void kfinal(const float* __restrict__ partials, float* __restrict__ out) {
    const int t = threadIdx.x;  // 64
    float L = (t < 32) ? partials[t] : 0.0f;
    float C = (t < 32) ? partials[32 + t] : 0.0f;
#pragma unroll
    for (int off = 1; off < 64; off <<= 1) {
        L += __shfl_xor(L, off);
        C += __shfl_xor(C, off);
    }
    if (t == 0) out[0] = (C > 0.0f) ? (L / C) : 0.0f;
}

extern "C" void kernel_launch(void* const* d_in, const int* in_sizes, int n_in,
                              void* d_out, int out_size, void* d_ws, size_t ws_size,
                              hipStream_t stream) {
    const float* emb  = (const float*)d_in[0];
    const int* labels = (const int*)d_in[1];
    float* out = (float*)d_out;

    char* w = (char*)d_ws;
    u16*   ENb  = (u16*)w;                       w += (size_t)NN * DD * 2;   // 4 MB
    float* invn = (float*)w;                     w += NN * 4;
    float* dapv = (float*)w;                     w += NN * 4;
    int*   posi = (int*)w;                       w += NN * 4;
    float* pM1  = (float*)w;                     w += (size_t)SL * NN * 4;   // 512 KB
    float* pMN  = (float*)w;                     w += (size_t)SL * NN * 4;   // 512 KB
    float* parts = (float*)w;

    kprep<<<NN / 4, 256, 0, stream>>>(emb, ENb, invn);
    kpos<<<NN / 256, 256, 0, stream>>>(labels, posi);
    kdap<<<NN / 4, 256, 0, stream>>>(emb, invn, posi, dapv);
    kmine<<<dim3(SL, NN / 128), 256, 0, stream>>>(ENb, labels, dapv, pM1, pMN);
    kcombine<<<NN / 256, 256, 0, stream>>>(posi, dapv, pM1, pMN, parts);
    kfinal<<<1, 64, 0, stream>>>(parts, out);
}

// Round 3
// 72.809 us; speedup vs baseline: 8.1584x; 2.3653x over previous
//
#include <hip/hip_runtime.h>
#include <math.h>

#define NN 8192
#define DD 256
#define MARGIN 0.2f
#define SL 16            // candidate slices (grid.x)
#define CPS (NN / SL)    // 512 candidates per slice
#define TILES (CPS / 128)
#define IMAX 0x7fffffff

typedef __attribute__((ext_vector_type(8))) short bf16x8;  // 8 bf16 (4 VGPRs)
typedef __attribute__((ext_vector_type(4))) float f32x4;
typedef unsigned int u32;
typedef unsigned short u16;

static __device__ __forceinline__ u16 f2bf(float f) {   // RNE fp32 -> bf16
    u32 u = __float_as_uint(f);
    return (u16)((u + 0x7fffu + ((u >> 16) & 1u)) >> 16);
}

static __device__ __forceinline__ void gload16(const void* g, void* l) {
    __builtin_amdgcn_global_load_lds((const __attribute__((address_space(1))) void*)g,
                                     (__attribute__((address_space(3))) void*)l, 16, 0, 0);
}

// ---------- kernel 1: norms + normalized bf16 matrix ----------
__global__ void kprep(const float* __restrict__ emb, u16* __restrict__ ENb,
                      float* __restrict__ invn) {
    const int wid = threadIdx.x >> 6, l = threadIdx.x & 63;
    const int row = blockIdx.x * 4 + wid;
    const float4 v = *(const float4*)&emb[(size_t)row * DD + l * 4];
    float ss = v.x * v.x + v.y * v.y + v.z * v.z + v.w * v.w;
#pragma unroll
    for (int o = 1; o < 64; o <<= 1) ss += __shfl_xor(ss, o);
    const float inv = 1.0f / fmaxf(sqrtf(ss), 1e-12f);
    if (l == 0) invn[row] = inv;
    ushort4 o4;
    o4.x = f2bf(v.x * inv); o4.y = f2bf(v.y * inv);
    o4.z = f2bf(v.z * inv); o4.w = f2bf(v.w * inv);
    *(ushort4*)&ENb[(size_t)row * DD + l * 4] = o4;
}

// ---------- kernel 2a: first two indices of each class ----------
// pos_idx[i] = argmax_j(same & ~eye) needs only j1[c] (first index of class c)
// and j2[c] (second index): pos_idx[i] = (i==j1) ? j2 : j1, valid iff j2 exists.
static __device__ __forceinline__ void comb2(int& a1, int& a2, int b1, int b2) {
    const int lo = min(a1, b1);
    const int hi = max(a1, b1);
    a2 = min(hi, min(a2, b2));
    a1 = lo;
}

__global__ void kclass(const int* __restrict__ labels, int* __restrict__ j12) {
    const int c = blockIdx.x;       // one block per class
    const int tid = threadIdx.x;    // 256
    int m1 = IMAX, m2 = IMAX;
    for (int j = tid; j < NN; j += 256) {   // ascending -> m1 < m2 per thread
        if (labels[j] == c) {
            if (m1 == IMAX) m1 = j;
            else if (m2 == IMAX) m2 = j;
        }
    }
#pragma unroll
    for (int o = 1; o < 64; o <<= 1)
        comb2(m1, m2, __shfl_xor(m1, o), __shfl_xor(m2, o));
    __shared__ int s1[4], s2[4];
    const int wave = tid >> 6, lane = tid & 63;
    if (lane == 0) { s1[wave] = m1; s2[wave] = m2; }
    __syncthreads();
    if (tid == 0) {
        comb2(m1, m2, s1[1], s2[1]);
        comb2(m1, m2, s1[2], s2[2]);
        comb2(m1, m2, s1[3], s2[3]);
        j12[2 * c] = m1;
        j12[2 * c + 1] = m2;
    }
}

// ---------- kernel 2b: posidx per anchor ----------
__global__ void kposidx(const int* __restrict__ labels, const int* __restrict__ j12,
                        int* __restrict__ posidx) {
    const int i = blockIdx.x * 256 + threadIdx.x;
    const int c = labels[i];
    const int j1 = j12[2 * c], j2 = j12[2 * c + 1];
    posidx[i] = (j2 == IMAX) ? -1 : ((i == j1) ? j2 : j1);
}

// ---------- kernel 3: exact fp32 d_ap ----------
__global__ void kdap(const float* __restrict__ emb, const float* __restrict__ invn,
                     const int* __restrict__ posidx, float* __restrict__ dap) {
    const int wid = threadIdx.x >> 6, l = threadIdx.x & 63;
    const int i = blockIdx.x * 4 + wid;
    const int p = posidx[i];
    float dv = 0.0f;
    if (p >= 0) {   // uniform per wave
        const float4 a = *(const float4*)&emb[(size_t)i * DD + l * 4];
        const float4 b = *(const float4*)&emb[(size_t)p * DD + l * 4];
        float s = a.x * b.x + a.y * b.y + a.z * b.z + a.w * b.w;
#pragma unroll
        for (int o = 1; o < 64; o <<= 1) s += __shfl_xor(s, o);
        const float sim = s * invn[i] * invn[p];
        dv = fminf(fmaxf(1.0f - sim, 0.0f), 2.0f);
    }
    if (l == 0) dap[i] = dv;
}

// ---------- kernel 4: MFMA mining ----------
// Per anchor, streaming sim-space maxes: MN = max sim over negatives,
// M1 = max sim over negatives with sim < hi (hi = 1 - d_ap).
__global__ __launch_bounds__(256) void kmine(
    const u16* __restrict__ ENb, const int* __restrict__ labels,
    const float* __restrict__ dap, float* __restrict__ pM1, float* __restrict__ pMN)
{
    __shared__ __align__(16) u16 As[128 * 64];   // candidates tile, chunk-swizzled
    __shared__ __align__(16) u16 Bs[128 * 64];   // anchors tile, chunk-swizzled
    __shared__ float Hi[128];
    __shared__ int LabA[128], LabC[128];
    __shared__ float RedN[2][128], RedS[2][128];

    const int tid = threadIdx.x;
    const int l = tid & 63;
    const int wid = tid >> 6;
    const int wr = wid >> 1;      // candidate half (M)
    const int wc = wid & 1;       // anchor half (N)
    const int slice = blockIdx.x;
    const int a0 = blockIdx.y * 128;

    if (tid < 128) {
        Hi[tid] = 1.0f - dap[a0 + tid];
        LabA[tid] = labels[a0 + tid];
    }

    const int frow = l & 15;      // row within 16x16 subtile
    const int fq = l >> 4;        // k-quarter 0..3
    const int fj = l & 7;         // row&7 for swizzle

    float mN[4], m1[4];
    int la[4]; float hiv[4];
#pragma unroll
    for (int n = 0; n < 4; ++n) { mN[n] = -INFINITY; m1[n] = -INFINITY; }

    f32x4 acc[4][4];

    for (int t = 0; t < TILES; ++t) {
        const int c0 = slice * CPS + t * 128;
#pragma unroll
        for (int m = 0; m < 4; ++m)
#pragma unroll
            for (int n = 0; n < 4; ++n) acc[m][n] = (f32x4){0.f, 0.f, 0.f, 0.f};

        for (int kc = 0; kc < 4; ++kc) {
            __syncthreads();     // prev compute/epilogue done; LDS reusable
            if (kc == 0 && tid < 128) LabC[tid] = labels[c0 + tid];
            // stage A,B: 1024 16B-chunks each; linear LDS dest, swizzled SOURCE
#pragma unroll
            for (int it = 0; it < 4; ++it) {
                const int idx = it * 256 + tid;
                const int row = idx >> 3;
                const int pch = idx & 7;
                const int lch = pch ^ (row & 7);
                gload16(&ENb[(size_t)(c0 + row) * DD + kc * 64 + lch * 8], &As[idx * 8]);
                gload16(&ENb[(size_t)(a0 + row) * DD + kc * 64 + lch * 8], &Bs[idx * 8]);
            }
            __syncthreads();     // staging drained (compiler emits vmcnt(0))
#pragma unroll
            for (int h = 0; h < 2; ++h) {
                bf16x8 af[4], bf[4];
                const int p = (4 * h + fq) ^ fj;   // physical chunk (swizzle-matched)
#pragma unroll
                for (int m = 0; m < 4; ++m)
                    af[m] = *(const bf16x8*)&As[(wr * 64 + m * 16 + frow) * 64 + p * 8];
#pragma unroll
                for (int n = 0; n < 4; ++n)
                    bf[n] = *(const bf16x8*)&Bs[(wc * 64 + n * 16 + frow) * 64 + p * 8];
#pragma unroll
                for (int m = 0; m < 4; ++m)
#pragma unroll
                    for (int n = 0; n < 4; ++n)
                        acc[m][n] = __builtin_amdgcn_mfma_f32_16x16x32_bf16(
                            af[m], bf[n], acc[m][n], 0, 0, 0);
            }
        }
        if (t == 0) {   // per-anchor constants (written pre-barrier at kernel start)
#pragma unroll
            for (int n = 0; n < 4; ++n) {
                la[n] = LabA[wc * 64 + n * 16 + frow];
                hiv[n] = Hi[wc * 64 + n * 16 + frow];
            }
        }
        int lcv[16];   // candidate labels for this tile: row = wr*64+m*16+fq*4+r
#pragma unroll
        for (int m = 0; m < 4; ++m)
#pragma unroll
            for (int r = 0; r < 4; ++r)
                lcv[m * 4 + r] = LabC[wr * 64 + m * 16 + fq * 4 + r];
        // epilogue: 6 VALU per element
#pragma unroll
        for (int m = 0; m < 4; ++m)
#pragma unroll
            for (int n = 0; n < 4; ++n) {
#pragma unroll
                for (int r = 0; r < 4; ++r) {
                    const float s = acc[m][n][r];
                    const float sel = (lcv[m * 4 + r] != la[n]) ? s : -INFINITY;
                    mN[n] = fmaxf(mN[n], sel);
                    const float sel2 = (sel < hiv[n]) ? sel : -INFINITY;
                    m1[n] = fmaxf(m1[n], sel2);
                }
            }
    }

    // reduce the 4 candidate row-groups (lanes l, l^16, l^32, l^48 share anchor)
#pragma unroll
    for (int n = 0; n < 4; ++n) {
        mN[n] = fmaxf(mN[n], __shfl_xor(mN[n], 16));
        mN[n] = fmaxf(mN[n], __shfl_xor(mN[n], 32));
        m1[n] = fmaxf(m1[n], __shfl_xor(m1[n], 16));
        m1[n] = fmaxf(m1[n], __shfl_xor(m1[n], 32));
    }
    __syncthreads();
    if (fq == 0) {
#pragma unroll
        for (int n = 0; n < 4; ++n) {
            RedN[wr][wc * 64 + n * 16 + frow] = mN[n];
            RedS[wr][wc * 64 + n * 16 + frow] = m1[n];
        }
    }
    __syncthreads();
    if (tid < 128) {   // combine the two candidate halves, write partials
        pMN[slice * NN + a0 + tid] = fmaxf(RedN[0][tid], RedN[1][tid]);
        pM1[slice * NN + a0 + tid] = fmaxf(RedS[0][tid], RedS[1][tid]);
    }
}

// ---------- kernel 5: combine slices -> per-block partial sums ----------
__global__ void kcombine(const int* __restrict__ posidx, const float* __restrict__ dap,
                         const float* __restrict__ pM1, const float* __restrict__ pMN,
                         float* __restrict__ partials)
{
    const int i = blockIdx.x * 256 + threadIdx.x;
    float loss = 0.0f, cnt = 0.0f;
    if (posidx[i] >= 0) {
        float s1 = -INFINITY, sN = -INFINITY;
#pragma unroll
        for (int s = 0; s < SL; ++s) {
            s1 = fmaxf(s1, pM1[s * NN + i]);
            sN = fmaxf(sN, pMN[s * NN + i]);
        }
        const float da = dap[i];
        const float lo = 1.0f - da - MARGIN;
        const float M = (s1 > lo) ? s1 : sN;   // has_semi ? best semi : hardest
        const float dan = fminf(fmaxf(1.0f - M, 0.0f), 2.0f);
        loss = fmaxf(da - dan + MARGIN, 0.0f);
        cnt = 1.0f;
    }
#pragma unroll
    for (int off = 1; off < 64; off <<= 1) {
        loss += __shfl_xor(loss, off);
        cnt  += __shfl_xor(cnt, off);
    }
    __shared__ float sl[4], sc[4];
    const int wave = threadIdx.x >> 6, lane = threadIdx.x & 63;
    if (lane == 0) { sl[wave] = loss; sc[wave] = cnt; }
    __syncthreads();
    if (threadIdx.x == 0) {
        partials[blockIdx.x]      = sl[0] + sl[1] + sl[2] + sl[3];
        partials[32 + blockIdx.x] = sc[0] + sc[1] + sc[2] + sc[3];
    }
}

// ---------- kernel 6: final scalar ----------
__global__ void kfinal(const float* __restrict__ partials, float* __restrict__ out) {
    const int t = threadIdx.x;  // 64
    float L = (t < 32) ? partials[t] : 0.0f;
    float C = (t < 32) ? partials[32 + t] : 0.0f;
#pragma unroll
    for (int off = 1; off < 64; off <<= 1) {
        L += __shfl_xor(L, off);
        C += __shfl_xor(C, off);
    }
    if (t == 0) out[0] = (C > 0.0f) ? (L / C) : 0.0f;
}

extern "C" void kernel_launch(void* const* d_in, const int* in_sizes, int n_in,
                              void* d_out, int out_size, void* d_ws, size_t ws_size,
                              hipStream_t stream) {
    const float* emb  = (const float*)d_in[0];
    const int* labels = (const int*)d_in[1];
    float* out = (float*)d_out;

    char* w = (char*)d_ws;
    u16*   ENb  = (u16*)w;                       w += (size_t)NN * DD * 2;   // 4 MB
    float* invn = (float*)w;                     w += NN * 4;
    float* dapv = (float*)w;                     w += NN * 4;
    int*   posi = (int*)w;                       w += NN * 4;
    int*   j12  = (int*)w;                       w += 256 * 4;
    float* pM1  = (float*)w;                     w += (size_t)SL * NN * 4;   // 512 KB
    float* pMN  = (float*)w;                     w += (size_t)SL * NN * 4;   // 512 KB
    float* parts = (float*)w;

    kprep<<<NN / 4, 256, 0, stream>>>(emb, ENb, invn);
    kclass<<<128, 256, 0, stream>>>(labels, j12);
    kposidx<<<NN / 256, 256, 0, stream>>>(labels, j12, posi);
    kdap<<<NN / 4, 256, 0, stream>>>(emb, invn, posi, dapv);
    kmine<<<dim3(SL, NN / 128), 256, 0, stream>>>(ENb, labels, dapv, pM1, pMN);
    kcombine<<<NN / 256, 256, 0, stream>>>(posi, dapv, pM1, pMN, parts);
    kfinal<<<1, 64, 0, stream>>>(parts, out);
}